// Round 1
// baseline (681.978 us; speedup 1.0000x reference)
//
#include <hip/hip_runtime.h>

// AssocScan: state_s = g_s * state_{s-1} + x_s, state_{-1} = prev.
// B=4, S=4096, D=4096, fp32. 16384 independent channels (b,d), scan along s.
// One thread per channel; 64-thread blocks (1 wave) -> 256 blocks = 1 wave/CU.
// Coalesced: lanes cover consecutive d. Latency hidden via U=16 double-buffered
// register pipeline (32 outstanding 256B loads/wave).

#define SCAN_B 4
#define SCAN_S 4096
#define SCAN_D 4096
#define U 16

__global__ __launch_bounds__(64, 1) void AssocScan_kernel(
    const float* __restrict__ G,   // gates  [B,S,D]
    const float* __restrict__ X,   // inputs [B,S,D]
    const float* __restrict__ P,   // prev   [B,1,D]
    float* __restrict__ O) {       // out    [B,S,D]
  const int bi = blockIdx.x;              // 0..255
  const int b  = bi >> 6;                 // 64 blocks per batch (D/64 = 64)
  const int d  = ((bi & 63) << 6) + threadIdx.x;

  const size_t base = (size_t)b * SCAN_S * SCAN_D + d;
  const float* g = G + base;
  const float* x = X + base;
  float*       o = O + base;

  float state = P[b * SCAN_D + d];

  float ga[U], xa[U], gb[U], xb[U];

  // Prime buffer A with s = 0..U-1
#pragma unroll
  for (int u = 0; u < U; ++u) {
    ga[u] = g[(size_t)u * SCAN_D];
    xa[u] = x[(size_t)u * SCAN_D];
  }

  size_t off = (size_t)U * SCAN_D;  // byte-element offset of buffer B's first s
  for (int sb = U; sb < SCAN_S; sb += U) {
    // Issue next block's loads (buffer B) before computing on A.
#pragma unroll
    for (int u = 0; u < U; ++u) {
      gb[u] = g[off + (size_t)u * SCAN_D];
      xb[u] = x[off + (size_t)u * SCAN_D];
    }
    // Compute + store buffer A (s = sb-U .. sb-1).
    const size_t aoff = off - (size_t)U * SCAN_D;
#pragma unroll
    for (int u = 0; u < U; ++u) {
      state = fmaf(ga[u], state, xa[u]);
      __builtin_nontemporal_store(state, o + aoff + (size_t)u * SCAN_D);
    }
    // Rotate B -> A (register renaming / cheap v_movs; VALU is idle anyway).
#pragma unroll
    for (int u = 0; u < U; ++u) {
      ga[u] = gb[u];
      xa[u] = xb[u];
    }
    off += (size_t)U * SCAN_D;
  }

  // Tail: last U elements sit in buffer A (s = S-U .. S-1).
#pragma unroll
  for (int u = 0; u < U; ++u) {
    state = fmaf(ga[u], state, xa[u]);
    __builtin_nontemporal_store(state, o + (size_t)(SCAN_S - U + u) * SCAN_D);
  }
}

extern "C" void kernel_launch(void* const* d_in, const int* in_sizes, int n_in,
                              void* d_out, int out_size, void* d_ws, size_t ws_size,
                              hipStream_t stream) {
  const float* gates  = (const float*)d_in[0];
  const float* inputs = (const float*)d_in[1];
  const float* prev   = (const float*)d_in[2];
  float* out = (float*)d_out;

  const int nblocks = SCAN_B * (SCAN_D / 64);  // 256
  AssocScan_kernel<<<nblocks, 64, 0, stream>>>(gates, inputs, prev, out);
}